// Round 6
// baseline (322.743 us; speedup 1.0000x reference)
//
#include <hip/hip_runtime.h>
#include <hip/hip_bf16.h>

// Problem constants (match reference)
constexpr int NE  = 8;
constexpr int T   = 2048;
constexpr int IN  = 2048;
constexpr int OUT = 2048;
constexpr int GS  = 64;
constexpr int G   = IN / GS;

// Stage-2 GEMM tiling (m97-style: global_load_lds + 2-barrier K-loop)
constexpr int BM = 128;
constexpr int BN = 64;
constexpr int BK = 64;

using short8  = __attribute__((ext_vector_type(8))) short;
using floatx4 = __attribute__((ext_vector_type(4))) float;

// async global->LDS, 16B per lane (LDS dest must be uniform-base + lane*16)
__device__ __forceinline__ void gld_lds16(const void* g, void* l) {
    __builtin_amdgcn_global_load_lds(
        (const __attribute__((address_space(1))) unsigned int*)g,
        (__attribute__((address_space(3))) unsigned int*)l, 16, 0, 0);
}

// ---- stage 0: x fp32 -> bf16 ----
__global__ __launch_bounds__(256)
void cvt_x_bf16(const float* __restrict__ x, __hip_bfloat16* __restrict__ xb) {
    const int i = (blockIdx.x * 256 + threadIdx.x) * 4;
    const float4 v = *(const float4*)(x + i);
    union { unsigned long long u; __hip_bfloat162 h2[2]; } p;
    p.h2[0] = __float22bfloat162_rn(float2{v.x, v.y});
    p.h2[1] = __float22bfloat162_rn(float2{v.z, v.w});
    *(unsigned long long*)(xb + i) = p.u;
}

// ---- stage 1: dequant qweight[E][IN][OUT] (int32 codes) -> Wt[E][OUT][IN] bf16 ----
// block = (n-chunk of 256, k-tile of 64, expert). Loads: lanes n-contiguous
// (256B/inst). Stores: per-thread 8 consecutive b128 into row n (L2-merged).
__global__ __launch_bounds__(256)
void dequant_wt(const int* __restrict__ qw, const float* __restrict__ snz,
                __hip_bfloat16* __restrict__ wt) {
    const int e  = blockIdx.z;
    const int k0 = blockIdx.y * 64;
    const int n  = blockIdx.x * 256 + threadIdx.x;
    const int g  = k0 >> 6;                    // one quant group per k-tile

    const float2 sz = ((const float2*)snz)[(size_t)e * G * OUT + (size_t)g * OUT + n];
    const float s = sz.x;
    const float c = sz.y - 8.0f * s;           // (q-8)*s+z == q*s+c

    const int* qp = qw + (size_t)e * IN * OUT + (size_t)k0 * OUT + n;
    __hip_bfloat16* wp = wt + (size_t)e * OUT * IN + (size_t)n * IN + k0;

#pragma unroll
    for (int kk = 0; kk < 64; kk += 8) {
        int q[8];
#pragma unroll
        for (int j = 0; j < 8; ++j)
            q[j] = qp[(size_t)(kk + j) * OUT];
        union { short8 v; __hip_bfloat162 h2[4]; } pb;
#pragma unroll
        for (int j = 0; j < 4; ++j) {
            const float f0 = (float)q[2 * j]     * s + c;
            const float f1 = (float)q[2 * j + 1] * s + c;
            pb.h2[j] = __float22bfloat162_rn(float2{f0, f1});
        }
        *(short8*)(wp + kk) = pb.v;
    }
}

// ---- stage 2: grouped GEMM, m97 structure ----
__global__ __launch_bounds__(256, 4)
void hqq_gemm(const __hip_bfloat16* __restrict__ xb,
              const __hip_bfloat16* __restrict__ wt,   // [E][OUT][IN] bf16
              const int* __restrict__ tpe,
              float* __restrict__ out) {
    const int tid = threadIdx.x;
    const int e   = blockIdx.z;
    const int tm  = blockIdx.y;
    const int n0  = blockIdx.x * BN;

    int b0 = 0;
    for (int i = 0; i < NE; ++i) {
        int c = tpe[i];
        if (i < e) b0 += c;
    }
    const int b1 = b0 + tpe[e];
    const int row0 = b0 + tm * BM;
    if (row0 >= b1) return;

    // unpadded (global_load_lds needs contiguous lane-order LDS)
    __shared__ __hip_bfloat16 As[BM * BK];   // [m][k]
    __shared__ __hip_bfloat16 Bs[BN * BK];   // [n][k]  (Wt rows are k-contiguous)

    // staging map: LDS offset = tid*16B + issue*4096B  (uniform base + lane*16)
    const int sm = tid >> 3;          // row within 32-row group
    const int sk = (tid & 7) * 8;     // k octet

    // MFMA decomposition: 4 waves stacked in m, each 32m x 64n
    const int lane = tid & 63;
    const int wid  = tid >> 6;
    const int wm = wid * 32;
    const int lm = lane & 15;
    const int lk = (lane >> 4) * 8;
    const int lq = (lane >> 4) * 4;

    floatx4 acc[2][4];
#pragma unroll
    for (int i = 0; i < 2; ++i)
#pragma unroll
        for (int j = 0; j < 4; ++j)
            acc[i][j] = (floatx4){0.f, 0.f, 0.f, 0.f};

    // per-thread global row for A staging (clamp to valid x row; rows >= b1
    // compute garbage that is never stored)
    int arow[4];
#pragma unroll
    for (int I = 0; I < 4; ++I) {
        int r = row0 + sm + 32 * I;
        arow[I] = r < T ? r : (T - 1);
    }
    const __hip_bfloat16* wbase = wt + (size_t)e * OUT * IN + (size_t)(n0 + sm) * IN;

    for (int k0 = 0; k0 < IN; k0 += BK) {
        // ---- async staging: 4 A-issues + 2 B-issues, drained by barrier ----
#pragma unroll
        for (int I = 0; I < 4; ++I)
            gld_lds16(xb + (size_t)arow[I] * IN + k0 + sk,
                      &As[(sm + 32 * I) * BK + sk]);
#pragma unroll
        for (int I = 0; I < 2; ++I)
            gld_lds16(wbase + (size_t)(32 * I) * IN + k0 + sk,
                      &Bs[(sm + 32 * I) * BK + sk]);

        __syncthreads();   // vmcnt(0) drain + barrier: tiles visible

        // ---- 16 MFMA per wave per k-tile ----
#pragma unroll
        for (int ks = 0; ks < BK; ks += 32) {
            short8 af[2], bfr[4];
#pragma unroll
            for (int i = 0; i < 2; ++i)
                af[i] = *(const short8*)&As[(wm + i * 16 + lm) * BK + ks + lk];
#pragma unroll
            for (int j = 0; j < 4; ++j)
                bfr[j] = *(const short8*)&Bs[(j * 16 + lm) * BK + ks + lk];
#pragma unroll
            for (int i = 0; i < 2; ++i)
#pragma unroll
                for (int j = 0; j < 4; ++j)
                    acc[i][j] = __builtin_amdgcn_mfma_f32_16x16x32_bf16(
                        af[i], bfr[j], acc[i][j], 0, 0, 0);
        }

        __syncthreads();   // LDS free for next k-tile
    }

    // ---- epilogue: exactly-once plain stores (C/D: col=lane&15, row=quad*4+reg) ----
#pragma unroll
    for (int i = 0; i < 2; ++i) {
#pragma unroll
        for (int r = 0; r < 4; ++r) {
            const int row = row0 + wm + i * 16 + lq + r;
            if (row < b1) {
                float* op = out + (size_t)row * OUT + n0 + lm;
#pragma unroll
                for (int j = 0; j < 4; ++j)
                    op[j * 16] = acc[i][j][r];
            }
        }
    }
}

extern "C" void kernel_launch(void* const* d_in, const int* in_sizes, int n_in,
                              void* d_out, int out_size, void* d_ws, size_t ws_size,
                              hipStream_t stream) {
    const float* x   = (const float*)d_in[0];
    const int*   qw  = (const int*)d_in[1];
    const float* snz = (const float*)d_in[2];
    const int*   tpe = (const int*)d_in[3];
    float* out = (float*)d_out;

    const size_t xb_bytes = (size_t)T * IN * sizeof(__hip_bfloat16);       // 8.4 MB
    __hip_bfloat16* xb = (__hip_bfloat16*)d_ws;
    __hip_bfloat16* wt = (__hip_bfloat16*)((char*)d_ws + xb_bytes);        // 67.1 MB

    cvt_x_bf16<<<(T * IN) / (256 * 4), 256, 0, stream>>>(x, xb);

    dequant_wt<<<dim3(OUT / 256, IN / 64, NE), 256, 0, stream>>>(qw, snz, wt);

    // every out row/col covered exactly once across (e, tm, n) -> no memset
    hqq_gemm<<<dim3(OUT / BN, T / BM, NE), 256, 0, stream>>>(xb, wt, tpe, out);
}

// Round 7
// 287.587 us; speedup vs baseline: 1.1222x; 1.1222x over previous
//
#include <hip/hip_runtime.h>
#include <hip/hip_bf16.h>

// Problem constants (match reference)
constexpr int NE  = 8;
constexpr int T   = 2048;
constexpr int IN  = 2048;
constexpr int OUT = 2048;
constexpr int GS  = 64;
constexpr int G   = IN / GS;

// Stage-2 GEMM tiling (m97-style: global_load_lds + 2-barrier K-loop)
constexpr int BM = 128;
constexpr int BN = 64;
constexpr int BK = 64;

using short8  = __attribute__((ext_vector_type(8))) short;
using floatx4 = __attribute__((ext_vector_type(4))) float;

// async global->LDS, 16B per lane (LDS dest = uniform base + lane*16)
__device__ __forceinline__ void gld_lds16(const void* g, void* l) {
    __builtin_amdgcn_global_load_lds(
        (const __attribute__((address_space(1))) unsigned int*)g,
        (__attribute__((address_space(3))) unsigned int*)l, 16, 0, 0);
}

// ---- stage 0: x fp32 -> bf16 ----
__global__ __launch_bounds__(256)
void cvt_x_bf16(const float* __restrict__ x, __hip_bfloat16* __restrict__ xb) {
    const int i = (blockIdx.x * 256 + threadIdx.x) * 4;
    const float4 v = *(const float4*)(x + i);
    union { unsigned long long u; __hip_bfloat162 h2[2]; } p;
    p.h2[0] = __float22bfloat162_rn(float2{v.x, v.y});
    p.h2[1] = __float22bfloat162_rn(float2{v.z, v.w});
    *(unsigned long long*)(xb + i) = p.u;
}

// ---- stage 1: dequant qweight[E][IN][OUT] (int32 codes) -> Wt[E][OUT][IN] bf16 ----
// Thread map: n = n0 + tid>>3, k-octet = (tid&7)*8. A wave's b128 store covers
// 8 n-rows x 128 B = 16 FULL 64B lines -> no L2 read-for-ownership (R6: scattered
// 16B stores caused 67 MB RFO fetch + 110 us). 32 loads batched in regs for ILP.
__global__ __launch_bounds__(256)
void dequant_wt(const int* __restrict__ qw, const float* __restrict__ snz,
                __hip_bfloat16* __restrict__ wt) {
    const int tid = threadIdx.x;
    const int e  = blockIdx.z;
    const int kc = blockIdx.y * 256;           // k-chunk of 256 (4 quant groups)
    const int n  = blockIdx.x * 32 + (tid >> 3);
    const int ko = (tid & 7) * 8;              // k-octet within 64-k tile

    const int* qp = qw + (size_t)e * IN * OUT + n;
    const float2* szp = (const float2*)snz + (size_t)e * G * OUT + n;

    // batch all 32 code loads + 4 scale/zero loads -> 32+ outstanding
    int q[4][8];
    float2 sz[4];
#pragma unroll
    for (int kt = 0; kt < 4; ++kt) {
        const int kb = kc + kt * 64 + ko;
#pragma unroll
        for (int j = 0; j < 8; ++j)
            q[kt][j] = qp[(size_t)(kb + j) * OUT];
        sz[kt] = szp[(size_t)((kc >> 6) + kt) * OUT];
    }

    __hip_bfloat16* wp = wt + (size_t)e * OUT * IN + (size_t)n * IN + kc + ko;
#pragma unroll
    for (int kt = 0; kt < 4; ++kt) {
        const float s = sz[kt].x;
        const float c = sz[kt].y - 8.0f * s;   // (q-8)*s+z == q*s+c
        union { short8 v; __hip_bfloat162 h2[4]; } pb;
#pragma unroll
        for (int j = 0; j < 4; ++j) {
            const float f0 = (float)q[kt][2 * j]     * s + c;
            const float f1 = (float)q[kt][2 * j + 1] * s + c;
            pb.h2[j] = __float22bfloat162_rn(float2{f0, f1});
        }
        *(short8*)(wp + kt * 64) = pb.v;       // wave: 16 full lines, no RFO
    }
}

// ---- stage 2: grouped GEMM, m97 structure (unchanged from R6) ----
__global__ __launch_bounds__(256, 4)
void hqq_gemm(const __hip_bfloat16* __restrict__ xb,
              const __hip_bfloat16* __restrict__ wt,   // [E][OUT][IN] bf16
              const int* __restrict__ tpe,
              float* __restrict__ out) {
    const int tid = threadIdx.x;
    const int e   = blockIdx.z;
    const int tm  = blockIdx.y;
    const int n0  = blockIdx.x * BN;

    int b0 = 0;
    for (int i = 0; i < NE; ++i) {
        int c = tpe[i];
        if (i < e) b0 += c;
    }
    const int b1 = b0 + tpe[e];
    const int row0 = b0 + tm * BM;
    if (row0 >= b1) return;

    __shared__ __hip_bfloat16 As[BM * BK];   // [m][k]
    __shared__ __hip_bfloat16 Bs[BN * BK];   // [n][k]

    const int sm = tid >> 3;
    const int sk = (tid & 7) * 8;

    const int lane = tid & 63;
    const int wid  = tid >> 6;
    const int wm = wid * 32;
    const int lm = lane & 15;
    const int lk = (lane >> 4) * 8;
    const int lq = (lane >> 4) * 4;

    floatx4 acc[2][4];
#pragma unroll
    for (int i = 0; i < 2; ++i)
#pragma unroll
        for (int j = 0; j < 4; ++j)
            acc[i][j] = (floatx4){0.f, 0.f, 0.f, 0.f};

    int arow[4];
#pragma unroll
    for (int I = 0; I < 4; ++I) {
        int r = row0 + sm + 32 * I;
        arow[I] = r < T ? r : (T - 1);
    }
    const __hip_bfloat16* wbase = wt + (size_t)e * OUT * IN + (size_t)(n0 + sm) * IN;

    for (int k0 = 0; k0 < IN; k0 += BK) {
#pragma unroll
        for (int I = 0; I < 4; ++I)
            gld_lds16(xb + (size_t)arow[I] * IN + k0 + sk,
                      &As[(sm + 32 * I) * BK + sk]);
#pragma unroll
        for (int I = 0; I < 2; ++I)
            gld_lds16(wbase + (size_t)(32 * I) * IN + k0 + sk,
                      &Bs[(sm + 32 * I) * BK + sk]);

        __syncthreads();

#pragma unroll
        for (int ks = 0; ks < BK; ks += 32) {
            short8 af[2], bfr[4];
#pragma unroll
            for (int i = 0; i < 2; ++i)
                af[i] = *(const short8*)&As[(wm + i * 16 + lm) * BK + ks + lk];
#pragma unroll
            for (int j = 0; j < 4; ++j)
                bfr[j] = *(const short8*)&Bs[(j * 16 + lm) * BK + ks + lk];
#pragma unroll
            for (int i = 0; i < 2; ++i)
#pragma unroll
                for (int j = 0; j < 4; ++j)
                    acc[i][j] = __builtin_amdgcn_mfma_f32_16x16x32_bf16(
                        af[i], bfr[j], acc[i][j], 0, 0, 0);
        }

        __syncthreads();
    }

#pragma unroll
    for (int i = 0; i < 2; ++i) {
#pragma unroll
        for (int r = 0; r < 4; ++r) {
            const int row = row0 + wm + i * 16 + lq + r;
            if (row < b1) {
                float* op = out + (size_t)row * OUT + n0 + lm;
#pragma unroll
                for (int j = 0; j < 4; ++j)
                    op[j * 16] = acc[i][j][r];
            }
        }
    }
}

extern "C" void kernel_launch(void* const* d_in, const int* in_sizes, int n_in,
                              void* d_out, int out_size, void* d_ws, size_t ws_size,
                              hipStream_t stream) {
    const float* x   = (const float*)d_in[0];
    const int*   qw  = (const int*)d_in[1];
    const float* snz = (const float*)d_in[2];
    const int*   tpe = (const int*)d_in[3];
    float* out = (float*)d_out;

    const size_t xb_bytes = (size_t)T * IN * sizeof(__hip_bfloat16);   // 8.4 MB
    __hip_bfloat16* xb = (__hip_bfloat16*)d_ws;
    __hip_bfloat16* wt = (__hip_bfloat16*)((char*)d_ws + xb_bytes);    // 67.1 MB

    cvt_x_bf16<<<(T * IN) / (256 * 4), 256, 0, stream>>>(x, xb);

    // grid: 64 n-chunks x 8 k-chunks x 8 experts = 4096 blocks
    dequant_wt<<<dim3(OUT / 32, IN / 256, NE), 256, 0, stream>>>(qw, snz, wt);

    hqq_gemm<<<dim3(OUT / BN, T / BM, NE), 256, 0, stream>>>(xb, wt, tpe, out);
}